// Round 10
// baseline (191.888 us; speedup 1.0000x reference)
//
#include <hip/hip_runtime.h>
#include <cstdint>
#include <cstddef>

#define B_ 8
#define T_ 4096
#define C_ 256
#define NC_ 256
#define L_ (T_ / NC_)   // 16 steps per chunk
#define M_ (B_ * T_)    // 32768 rows

typedef float f32x4 __attribute__((ext_vector_type(4)));
typedef short bf16x8 __attribute__((ext_vector_type(8)));

__device__ __forceinline__ unsigned short f2b(float f) {
    unsigned int u = __float_as_uint(f);
    u += 0x7fffu + ((u >> 16) & 1u);   // round-to-nearest-even
    return (unsigned short)(u >> 16);
}
__device__ __forceinline__ float b2f(unsigned short h) {
    return __uint_as_float(((unsigned int)h) << 16);
}

// ---------------- fused f32->bf16 convert: x (4096 blocks) + 4 weights --------
__global__ __launch_bounds__(256) void cvt_all(const float* __restrict__ x,
                                               const float* __restrict__ Wk,
                                               const float* __restrict__ Wv,
                                               const float* __restrict__ Wr,
                                               const float* __restrict__ Wo,
                                               unsigned short* __restrict__ xb,
                                               unsigned short* __restrict__ wb) {
    const int bid = blockIdx.x;
    const float* src;
    unsigned short* dst;
    size_t base;
    if (bid < 4096) {
        src = x; dst = xb;
        base = (size_t)bid * 2048;
    } else {
        const int r = bid - 4096;          // 0..127
        const int mat = r >> 5;            // 0..3
        src = (mat == 0) ? Wk : (mat == 1) ? Wv : (mat == 2) ? Wr : Wo;
        dst = wb + (size_t)mat * 65536;
        base = (size_t)(r & 31) * 2048;
    }
    const size_t i = base + (size_t)threadIdx.x * 8;
    float4 a = *(const float4*)(src + i);
    float4 b = *(const float4*)(src + i + 4);
    bf16x8 o;
    o[0] = (short)f2b(a.x); o[1] = (short)f2b(a.y);
    o[2] = (short)f2b(a.z); o[3] = (short)f2b(a.w);
    o[4] = (short)f2b(b.x); o[5] = (short)f2b(b.y);
    o[6] = (short)f2b(b.z); o[7] = (short)f2b(b.w);
    *(bf16x8*)(dst + i) = o;
}

// ---------------- QKV GEMM v8: stage ALIASED into wlds -> 4 blocks/CU ---------
// O[m,n] = sum_k A[m,k]*W[n,k]. Grid (M/64, 4). 3 mats looped; W prefetched;
// fused pass1 scan (R9). NEW: the f32 output stage aliases the wlds region
// (never both live: stage written only after MFMA reads of wlds complete, wlds
// refilled only after the loop-top barrier). LDS 51200 -> 33792 B = 4 blk/CU.
// Cost: +1 barrier per mat. Staged full-line stores retained (R4 lesson).
__global__ __launch_bounds__(256, 4) void gemm_qkv(const unsigned short* __restrict__ A,
                                                   const unsigned short* __restrict__ w0,
                                                   const unsigned short* __restrict__ w1,
                                                   const unsigned short* __restrict__ w2,
                                                   const float* __restrict__ decay,
                                                   float* __restrict__ f0,
                                                   float* __restrict__ f1,
                                                   unsigned short* __restrict__ b2,
                                                   float* __restrict__ sp,
                                                   float* __restrict__ sq,
                                                   float* __restrict__ so) {
    __shared__ unsigned short wlds[64 * 264];   // 33792 B (stage aliases inside)
    const int tid = threadIdx.x;
    const int wave = tid >> 6, lane = tid & 63;
    const int quad = lane >> 4, l16 = lane & 15;
    const int m0 = blockIdx.x * 64 + wave * 16;
    const int n0 = blockIdx.y * 64;
    float* myst = (float*)wlds + wave * 1088;   // 16*68 floats per wave

    bf16x8 af[8];
    {
        const unsigned short* Ar = A + (size_t)(m0 + l16) * C_ + quad * 8;
#pragma unroll
        for (int kc = 0; kc < 8; ++kc) af[kc] = *(const bf16x8*)(Ar + kc * 32);
    }

    const int r = tid >> 5;              // 0..7
    const int cs = (tid & 31) * 8;       // short offset, 16 B per lane

    bf16x8 tmp[8];
#pragma unroll
    for (int it = 0; it < 8; ++it)
        tmp[it] = *(const bf16x8*)(w0 + (size_t)(n0 + it * 8 + r) * C_ + cs);

    float kreg[16], vreg[16];            // chunk-local k/v columns (per channel)

    for (int mat = 0; mat < 3; ++mat) {
        __syncthreads();                 // prev mat's stage writes/reads done
#pragma unroll
        for (int it = 0; it < 8; ++it)
            *(bf16x8*)(wlds + (it * 8 + r) * 264 + cs) = tmp[it];
        __syncthreads();                 // wlds (W tile) visible to all waves

        if (mat < 2) {                   // prefetch next W; retires under MFMAs
            const unsigned short* Wn = (mat == 0) ? w1 : w2;
#pragma unroll
            for (int it = 0; it < 8; ++it)
                tmp[it] = *(const bf16x8*)(Wn + (size_t)(n0 + it * 8 + r) * C_ + cs);
        }

        f32x4 acc[4];
#pragma unroll
        for (int nt = 0; nt < 4; ++nt) acc[nt] = (f32x4){0.f, 0.f, 0.f, 0.f};
#pragma unroll
        for (int nt = 0; nt < 4; ++nt) {
            const unsigned short* wrow = wlds + (nt * 16 + l16) * 264 + quad * 8;
#pragma unroll
            for (int kc = 0; kc < 8; ++kc) {
                bf16x8 wf = *(const bf16x8*)(wrow + kc * 32);
                acc[nt] = __builtin_amdgcn_mfma_f32_16x16x32_bf16(af[kc], wf, acc[nt], 0, 0, 0);
            }
        }

        __syncthreads();                 // all waves' MFMA reads of wlds done
#pragma unroll
        for (int nt = 0; nt < 4; ++nt)
#pragma unroll
            for (int i = 0; i < 4; ++i)
                myst[(quad * 4 + i) * 68 + nt * 16 + l16] = acc[nt][i];
#pragma unroll
        for (int rr = 0; rr < 4; ++rr) {
            const int row = rr * 4 + quad;
            float4 t4 = *(const float4*)&myst[row * 68 + l16 * 4];
            const size_t gidx = (size_t)(m0 + row) * C_ + n0 + l16 * 4;
            if (mat == 0) {
                *(float4*)(f0 + gidx) = t4;
            } else if (mat == 1) {
                *(float4*)(f1 + gidx) = t4;
            } else {
                ushort4 s4;
                s4.x = f2b(1.f / (1.f + __expf(-t4.x)));
                s4.y = f2b(1.f / (1.f + __expf(-t4.y)));
                s4.z = f2b(1.f / (1.f + __expf(-t4.z)));
                s4.w = f2b(1.f / (1.f + __expf(-t4.w)));
                *(ushort4*)(b2 + gidx) = s4;
            }
        }

        // ---- fused pass1: snapshot this wave's chunk column, scan at mat==1 --
        // myst is per-wave (wave-ordered LDS; no extra barrier needed).
        if (mat == 0) {
#pragma unroll
            for (int j = 0; j < L_; ++j) kreg[j] = myst[j * 68 + lane];
        } else if (mat == 1) {
#pragma unroll
            for (int j = 0; j < L_; ++j) vreg[j] = myst[j * 68 + lane];
            const int ch = n0 + lane;
            const float w = decay[ch] * (1.0f / T_);
            float p = 0.f, q = 0.f, o = -1e38f;
#pragma unroll
            for (int j = 0; j < L_; ++j) {
                float wo = w + o;
                float no = fmaxf(wo, kreg[j]);
                float a2 = __expf(wo - no), b2s = __expf(kreg[j] - no);
                p = a2 * p + b2s * vreg[j];
                q = a2 * q + b2s;
                o = no;
            }
            const int bb = m0 / T_;
            const int chunk = (m0 % T_) / L_;
            const size_t idx = ((size_t)bb * NC_ + chunk) * C_ + ch;
            sp[idx] = p; sq[idx] = q; so[idx] = o;
        }
    }
}

// ---------------- output GEMM v4: stage aliased into wlds -> 4 blocks/CU ------
__global__ __launch_bounds__(256, 4) void gemm_out(const unsigned short* __restrict__ A,
                                                   const unsigned short* __restrict__ w0,
                                                   float* __restrict__ f0) {
    __shared__ unsigned short wlds[64 * 264];   // 33792 B (stage aliases inside)
    const int tid = threadIdx.x;
    const int wave = tid >> 6, lane = tid & 63;
    const int quad = lane >> 4, l16 = lane & 15;
    const int m0 = blockIdx.x * 64 + wave * 16;
    const int n0 = blockIdx.y * 64;
    float* myst = (float*)wlds + wave * 1088;

    {
        const int r = tid >> 5;
        const int cs = (tid & 31) * 8;
        bf16x8 tmp[8];
#pragma unroll
        for (int it = 0; it < 8; ++it)
            tmp[it] = *(const bf16x8*)(w0 + (size_t)(n0 + it * 8 + r) * C_ + cs);
#pragma unroll
        for (int it = 0; it < 8; ++it)
            *(bf16x8*)(wlds + (it * 8 + r) * 264 + cs) = tmp[it];
    }
    __syncthreads();

    bf16x8 af[8];
    {
        const unsigned short* Ar = A + (size_t)(m0 + l16) * C_ + quad * 8;
#pragma unroll
        for (int kc = 0; kc < 8; ++kc) af[kc] = *(const bf16x8*)(Ar + kc * 32);
    }

    f32x4 acc[4];
#pragma unroll
    for (int nt = 0; nt < 4; ++nt) acc[nt] = (f32x4){0.f, 0.f, 0.f, 0.f};
#pragma unroll
    for (int nt = 0; nt < 4; ++nt) {
        const unsigned short* wrow = wlds + (nt * 16 + l16) * 264 + quad * 8;
#pragma unroll
        for (int kc = 0; kc < 8; ++kc) {
            bf16x8 wf = *(const bf16x8*)(wrow + kc * 32);
            acc[nt] = __builtin_amdgcn_mfma_f32_16x16x32_bf16(af[kc], wf, acc[nt], 0, 0, 0);
        }
    }

    __syncthreads();                     // all waves' MFMA reads of wlds done
#pragma unroll
    for (int nt = 0; nt < 4; ++nt)
#pragma unroll
        for (int i = 0; i < 4; ++i)
            myst[(quad * 4 + i) * 68 + nt * 16 + l16] = acc[nt][i];
#pragma unroll
    for (int rr = 0; rr < 4; ++rr) {
        const int row = rr * 4 + quad;
        float4 t4 = *(const float4*)&myst[row * 68 + l16 * 4];
        *(float4*)(f0 + (size_t)(m0 + row) * C_ + n0 + l16 * 4) = t4;
    }
}

// ---------------- WKV combine: PARALLEL segmented scan over chunks ------------
__global__ __launch_bounds__(256) void wkv_combine_par(const float* __restrict__ decay,
                                                       float* __restrict__ sp,
                                                       float* __restrict__ sq,
                                                       float* __restrict__ so) {
    __shared__ float tp[16][17], tq[16][17], to[16][17];
    const int tid = threadIdx.x;
    const int cgi = tid >> 4;
    const int cl = tid & 15;
    const int b = blockIdx.x;
    const int c = blockIdx.y * 16 + cl;
    const float wL = decay[c] * (1.0f / T_) * (float)L_;
    const float wL16 = wL * 16.0f;
    const size_t base = ((size_t)b * NC_ + (size_t)cgi * 16) * C_ + c;

    float p = 0.f, q = 0.f, o = -1e38f;
#pragma unroll 4
    for (int j = 0; j < 16; ++j) {
        size_t idx = base + (size_t)j * C_;
        float lp = sp[idx], lq = sq[idx], lo = so[idx];
        float ow = o + wL;
        float no = fmaxf(ow, lo);
        float ea = __expf(ow - no), eb = __expf(lo - no);
        p = ea * p + eb * lp;
        q = ea * q + eb * lq;
        o = no;
    }
    tp[cgi][cl] = p; tq[cgi][cl] = q; to[cgi][cl] = o;

    float ip = p, iq = q, io = o;
#pragma unroll
    for (int off = 1; off < 16; off <<= 1) {
        __syncthreads();
        float ap = 0.f, aq = 0.f, ao = 0.f;
        const bool doit = (cgi >= off);
        if (doit) { ap = tp[cgi - off][cl]; aq = tq[cgi - off][cl]; ao = to[cgi - off][cl]; }
        __syncthreads();
        if (doit) {
            float ow = ao + (float)off * wL16;
            float no = fmaxf(ow, io);
            float ea = __expf(ow - no), eb = __expf(io - no);
            ip = ea * ap + eb * ip;
            iq = ea * aq + eb * iq;
            io = no;
            tp[cgi][cl] = ip; tq[cgi][cl] = iq; to[cgi][cl] = io;
        }
    }
    __syncthreads();

    float ep, eq, eo;
    if (cgi == 0) { ep = 0.f; eq = 0.f; eo = -1e38f; }
    else          { ep = tp[cgi - 1][cl]; eq = tq[cgi - 1][cl]; eo = to[cgi - 1][cl]; }

    for (int j = 0; j < 16; ++j) {
        size_t idx = base + (size_t)j * C_;
        float lp = sp[idx], lq = sq[idx], lo = so[idx];
        sp[idx] = ep; sq[idx] = eq; so[idx] = eo;
        float ow = eo + wL;
        float no = fmaxf(ow, lo);
        float ea = __expf(ow - no), eb = __expf(lo - no);
        ep = ea * ep + eb * lp;
        eq = ea * eq + eb * lq;
        eo = no;
    }
}

// ---------------- WKV pass 2 + LayerNorm + gate (known-good) -------------------
__global__ __launch_bounds__(256, 8) void wkv_pass2_ln(const float* __restrict__ k,
                                                       const float* __restrict__ v,
                                                       const unsigned short* __restrict__ sr,
                                                       const float* __restrict__ decay,
                                                       const float* __restrict__ first,
                                                       const float* __restrict__ lw,
                                                       const float* __restrict__ lb,
                                                       const float* __restrict__ sp,
                                                       const float* __restrict__ sq,
                                                       const float* __restrict__ so,
                                                       unsigned short* __restrict__ z) {
    __shared__ float tile[16][264];
    __shared__ float mu_s[16], rs_s[16];
    const int c = threadIdx.x, chunk = blockIdx.x, b = blockIdx.y;
    const int wave = c >> 6, lane = c & 63;
    const float w = decay[c] * (1.0f / T_);
    const float u = first[c] * (1.0f / T_);
    const float gw = lw[c], gb = lb[c];
    size_t sidx = ((size_t)b * NC_ + chunk) * C_ + c;
    float p = sp[sidx], q = sq[sidx], o = so[sidx];
    size_t base = ((size_t)b * T_ + (size_t)chunk * L_) * C_ + c;

    for (int t = 0; t < L_; t += 8) {
        float kk[8], vv[8];
#pragma unroll
        for (int j = 0; j < 8; ++j) {
            kk[j] = k[base + (size_t)(t + j) * C_];
            vv[j] = v[base + (size_t)(t + j) * C_];
        }
#pragma unroll
        for (int j = 0; j < 8; ++j) {
            float uk = u + kk[j];
            float no = fmaxf(o, uk);
            float a = __expf(o - no), bb = __expf(uk - no);
            tile[t + j][c] = (a * p + bb * vv[j]) / (a * q + bb);
            float wo = w + o;
            float no2 = fmaxf(wo, kk[j]);
            float a2 = __expf(wo - no2), b2 = __expf(kk[j] - no2);
            p = a2 * p + b2 * vv[j];
            q = a2 * q + b2;
            o = no2;
        }
    }
    __syncthreads();
#pragma unroll
    for (int r = 0; r < 4; ++r) {
        const int j = wave * 4 + r;
        float4 t4 = *(const float4*)&tile[j][lane * 4];
        float s = t4.x + t4.y + t4.z + t4.w;
        float ss = t4.x * t4.x + t4.y * t4.y + t4.z * t4.z + t4.w * t4.w;
#pragma unroll
        for (int m = 1; m < 64; m <<= 1) {
            s += __shfl_xor(s, m, 64);
            ss += __shfl_xor(ss, m, 64);
        }
        if (lane == 0) {
            float mu = s * (1.f / C_);
            mu_s[j] = mu;
            rs_s[j] = rsqrtf(ss * (1.f / C_) - mu * mu + 1e-5f);
        }
    }
    __syncthreads();
#pragma unroll
    for (int j = 0; j < L_; ++j) {
        float zz = (tile[j][c] - mu_s[j]) * rs_s[j] * gw + gb;
        zz *= b2f(sr[base + (size_t)j * C_]);
        z[base + (size_t)j * C_] = f2b(zz);
    }
}

extern "C" void kernel_launch(void* const* d_in, const int* in_sizes, int n_in,
                              void* d_out, int out_size, void* d_ws, size_t ws_size,
                              hipStream_t stream) {
    const float* x     = (const float*)d_in[0];
    const float* Wk    = (const float*)d_in[1];
    const float* Wv    = (const float*)d_in[2];
    const float* Wr    = (const float*)d_in[3];
    const float* Wo    = (const float*)d_in[4];
    const float* decay = (const float*)d_in[5];
    const float* first = (const float*)d_in[6];
    const float* lnw   = (const float*)d_in[7];
    const float* lnb   = (const float*)d_in[8];
    float* out = (float*)d_out;

    char* ws = (char*)d_ws;
    const size_t NE = (size_t)M_ * C_;              // 8388608
    unsigned short* wb  = (unsigned short*)ws; ws += 4 * 65536 * 2;  // wk|wv|wr|wo
    unsigned short* xb  = (unsigned short*)ws; ws += NE * 2;
    float* kbuf = (float*)ws; ws += NE * 4;
    float* vbuf = (float*)ws; ws += NE * 4;
    unsigned short* srb = (unsigned short*)ws; ws += NE * 2;
    unsigned short* zb  = (unsigned short*)ws; ws += NE * 2;
    const size_t SE = (size_t)B_ * NC_ * C_;        // 524288
    float* sp = (float*)ws; ws += SE * 4;
    float* sq = (float*)ws; ws += SE * 4;
    float* so = (float*)ws; ws += SE * 4;
    unsigned short* wkb = wb;
    unsigned short* wvb = wb + 65536;
    unsigned short* wrb = wb + 2 * 65536;
    unsigned short* wob = wb + 3 * 65536;

    cvt_all<<<4096 + 128, 256, 0, stream>>>(x, Wk, Wv, Wr, Wo, xb, wb);

    // QKV + fused pass1: 512 row-blocks x 4 col-strips = 2048 blocks
    gemm_qkv<<<dim3(M_ / 64, 4), 256, 0, stream>>>(xb, wkb, wvb, wrb, decay,
                                                   kbuf, vbuf, srb, sp, sq, so);

    wkv_combine_par<<<dim3(B_, C_ / 16), 256, 0, stream>>>(decay, sp, sq, so);
    wkv_pass2_ln<<<dim3(NC_, B_), 256, 0, stream>>>(kbuf, vbuf, srb, decay, first,
                                                    lnw, lnb, sp, sq, so, zb);

    // Output GEMM: 512 row-blocks x 4 col-strips = 2048 blocks
    gemm_out<<<dim3(M_ / 64, 4), 256, 0, stream>>>(zb, wob, out);
}

// Round 12
// 166.770 us; speedup vs baseline: 1.1506x; 1.1506x over previous
//
#include <hip/hip_runtime.h>
#include <cstdint>
#include <cstddef>

#define B_ 8
#define T_ 4096
#define C_ 256
#define NC_ 256
#define L_ (T_ / NC_)   // 16 steps per chunk
#define M_ (B_ * T_)    // 32768 rows

typedef float f32x4 __attribute__((ext_vector_type(4)));
typedef short bf16x8 __attribute__((ext_vector_type(8)));

__device__ __forceinline__ unsigned short f2b(float f) {
    unsigned int u = __float_as_uint(f);
    u += 0x7fffu + ((u >> 16) & 1u);   // round-to-nearest-even
    return (unsigned short)(u >> 16);
}
__device__ __forceinline__ float b2f(unsigned short h) {
    return __uint_as_float(((unsigned int)h) << 16);
}

// ---------------- fused f32->bf16 convert: x (4096 blocks) + 4 weights --------
__global__ __launch_bounds__(256) void cvt_all(const float* __restrict__ x,
                                               const float* __restrict__ Wk,
                                               const float* __restrict__ Wv,
                                               const float* __restrict__ Wr,
                                               const float* __restrict__ Wo,
                                               unsigned short* __restrict__ xb,
                                               unsigned short* __restrict__ wb) {
    const int bid = blockIdx.x;
    const float* src;
    unsigned short* dst;
    size_t base;
    if (bid < 4096) {
        src = x; dst = xb;
        base = (size_t)bid * 2048;
    } else {
        const int r = bid - 4096;          // 0..127
        const int mat = r >> 5;            // 0..3
        src = (mat == 0) ? Wk : (mat == 1) ? Wv : (mat == 2) ? Wr : Wo;
        dst = wb + (size_t)mat * 65536;
        base = (size_t)(r & 31) * 2048;
    }
    const size_t i = base + (size_t)threadIdx.x * 8;
    float4 a = *(const float4*)(src + i);
    float4 b = *(const float4*)(src + i + 4);
    bf16x8 o;
    o[0] = (short)f2b(a.x); o[1] = (short)f2b(a.y);
    o[2] = (short)f2b(a.z); o[3] = (short)f2b(a.w);
    o[4] = (short)f2b(b.x); o[5] = (short)f2b(b.y);
    o[6] = (short)f2b(b.z); o[7] = (short)f2b(b.w);
    *(bf16x8*)(dst + i) = o;
}

// ---------------- QKV GEMM (R9 known-good): separate stage, fused pass1 -------
// O[m,n] = sum_k A[m,k]*W[n,k]. Grid (M/64, 4). 3 mats looped; W prefetched;
// fused pass1 scan. R10/R11 lesson: aliasing the stage into wlds produces
// schedule-dependent nondeterminism -- keep the SEPARATE stage buffer.
__global__ __launch_bounds__(256, 3) void gemm_qkv(const unsigned short* __restrict__ A,
                                                   const unsigned short* __restrict__ w0,
                                                   const unsigned short* __restrict__ w1,
                                                   const unsigned short* __restrict__ w2,
                                                   const float* __restrict__ decay,
                                                   float* __restrict__ f0,
                                                   float* __restrict__ f1,
                                                   unsigned short* __restrict__ b2,
                                                   float* __restrict__ sp,
                                                   float* __restrict__ sq,
                                                   float* __restrict__ so) {
    __shared__ unsigned short wlds[64 * 264];   // 33792 B
    __shared__ float stage[4][16 * 68];         // 17408 B (total 51200 -> 3 blk/CU)
    const int tid = threadIdx.x;
    const int wave = tid >> 6, lane = tid & 63;
    const int quad = lane >> 4, l16 = lane & 15;
    const int m0 = blockIdx.x * 64 + wave * 16;
    const int n0 = blockIdx.y * 64;
    float* myst = stage[wave];

    bf16x8 af[8];
    {
        const unsigned short* Ar = A + (size_t)(m0 + l16) * C_ + quad * 8;
#pragma unroll
        for (int kc = 0; kc < 8; ++kc) af[kc] = *(const bf16x8*)(Ar + kc * 32);
    }

    const int r = tid >> 5;              // 0..7
    const int cs = (tid & 31) * 8;       // short offset, 16 B per lane

    bf16x8 tmp[8];
#pragma unroll
    for (int it = 0; it < 8; ++it)
        tmp[it] = *(const bf16x8*)(w0 + (size_t)(n0 + it * 8 + r) * C_ + cs);

    float kreg[16], vreg[16];            // chunk-local k/v columns (per channel)

    for (int mat = 0; mat < 3; ++mat) {
        __syncthreads();                 // prev mat's wlds reads done
#pragma unroll
        for (int it = 0; it < 8; ++it)
            *(bf16x8*)(wlds + (it * 8 + r) * 264 + cs) = tmp[it];
        __syncthreads();                 // wlds visible to all waves

        if (mat < 2) {                   // prefetch next W; retires under MFMAs
            const unsigned short* Wn = (mat == 0) ? w1 : w2;
#pragma unroll
            for (int it = 0; it < 8; ++it)
                tmp[it] = *(const bf16x8*)(Wn + (size_t)(n0 + it * 8 + r) * C_ + cs);
        }

        f32x4 acc[4];
#pragma unroll
        for (int nt = 0; nt < 4; ++nt) acc[nt] = (f32x4){0.f, 0.f, 0.f, 0.f};
#pragma unroll
        for (int nt = 0; nt < 4; ++nt) {
            const unsigned short* wrow = wlds + (nt * 16 + l16) * 264 + quad * 8;
#pragma unroll
            for (int kc = 0; kc < 8; ++kc) {
                bf16x8 wf = *(const bf16x8*)(wrow + kc * 32);
                acc[nt] = __builtin_amdgcn_mfma_f32_16x16x32_bf16(af[kc], wf, acc[nt], 0, 0, 0);
            }
        }

#pragma unroll
        for (int nt = 0; nt < 4; ++nt)
#pragma unroll
            for (int i = 0; i < 4; ++i)
                myst[(quad * 4 + i) * 68 + nt * 16 + l16] = acc[nt][i];
#pragma unroll
        for (int rr = 0; rr < 4; ++rr) {
            const int row = rr * 4 + quad;
            float4 t4 = *(const float4*)&myst[row * 68 + l16 * 4];
            const size_t gidx = (size_t)(m0 + row) * C_ + n0 + l16 * 4;
            if (mat == 0) {
                *(float4*)(f0 + gidx) = t4;
            } else if (mat == 1) {
                *(float4*)(f1 + gidx) = t4;
            } else {
                ushort4 s4;
                s4.x = f2b(1.f / (1.f + __expf(-t4.x)));
                s4.y = f2b(1.f / (1.f + __expf(-t4.y)));
                s4.z = f2b(1.f / (1.f + __expf(-t4.z)));
                s4.w = f2b(1.f / (1.f + __expf(-t4.w)));
                *(ushort4*)(b2 + gidx) = s4;
            }
        }

        // ---- fused pass1: snapshot this wave's chunk column, scan at mat==1 --
        // myst is per-wave (wave-ordered LDS; separate buffer from wlds).
        if (mat == 0) {
#pragma unroll
            for (int j = 0; j < L_; ++j) kreg[j] = myst[j * 68 + lane];
        } else if (mat == 1) {
#pragma unroll
            for (int j = 0; j < L_; ++j) vreg[j] = myst[j * 68 + lane];
            const int ch = n0 + lane;
            const float w = decay[ch] * (1.0f / T_);
            float p = 0.f, q = 0.f, o = -1e38f;
#pragma unroll
            for (int j = 0; j < L_; ++j) {
                float wo = w + o;
                float no = fmaxf(wo, kreg[j]);
                float a2 = __expf(wo - no), b2s = __expf(kreg[j] - no);
                p = a2 * p + b2s * vreg[j];
                q = a2 * q + b2s;
                o = no;
            }
            const int bb = m0 / T_;
            const int chunk = (m0 % T_) / L_;
            const size_t idx = ((size_t)bb * NC_ + chunk) * C_ + ch;
            sp[idx] = p; sq[idx] = q; so[idx] = o;
        }
    }
}

// ---------------- output GEMM v6: 4 n-strips looped, A-frags loaded ONCE ------
// Same mechanism as gemm_qkv's 3-mat loop (proven -5us there): grid (M/64) =
// 512 blocks; af reused across all 4 strips (A traffic /4); next strip's W
// prefetched into regs under current strip's MFMAs. Separate stage buffer.
__global__ __launch_bounds__(256, 3) void gemm_out(const unsigned short* __restrict__ A,
                                                   const unsigned short* __restrict__ w0,
                                                   float* __restrict__ f0) {
    __shared__ unsigned short wlds[64 * 264];   // 33792 B
    __shared__ float stage[4][16 * 68];         // 17408 B
    const int tid = threadIdx.x;
    const int wave = tid >> 6, lane = tid & 63;
    const int quad = lane >> 4, l16 = lane & 15;
    const int m0 = blockIdx.x * 64 + wave * 16;
    float* myst = stage[wave];

    bf16x8 af[8];
    {
        const unsigned short* Ar = A + (size_t)(m0 + l16) * C_ + quad * 8;
#pragma unroll
        for (int kc = 0; kc < 8; ++kc) af[kc] = *(const bf16x8*)(Ar + kc * 32);
    }

    const int r = tid >> 5;              // 0..7
    const int cs = (tid & 31) * 8;       // short offset, 16 B per lane

    bf16x8 tmp[8];
#pragma unroll
    for (int it = 0; it < 8; ++it)
        tmp[it] = *(const bf16x8*)(w0 + (size_t)(it * 8 + r) * C_ + cs);

    for (int s = 0; s < 4; ++s) {
        const int n0 = s * 64;
        __syncthreads();                 // prev strip's wlds reads done
#pragma unroll
        for (int it = 0; it < 8; ++it)
            *(bf16x8*)(wlds + (it * 8 + r) * 264 + cs) = tmp[it];
        __syncthreads();                 // wlds visible to all waves

        if (s < 3) {                     // prefetch next strip's W rows
#pragma unroll
            for (int it = 0; it < 8; ++it)
                tmp[it] = *(const bf16x8*)(w0 + (size_t)(n0 + 64 + it * 8 + r) * C_ + cs);
        }

        f32x4 acc[4];
#pragma unroll
        for (int nt = 0; nt < 4; ++nt) acc[nt] = (f32x4){0.f, 0.f, 0.f, 0.f};
#pragma unroll
        for (int nt = 0; nt < 4; ++nt) {
            const unsigned short* wrow = wlds + (nt * 16 + l16) * 264 + quad * 8;
#pragma unroll
            for (int kc = 0; kc < 8; ++kc) {
                bf16x8 wf = *(const bf16x8*)(wrow + kc * 32);
                acc[nt] = __builtin_amdgcn_mfma_f32_16x16x32_bf16(af[kc], wf, acc[nt], 0, 0, 0);
            }
        }

#pragma unroll
        for (int nt = 0; nt < 4; ++nt)
#pragma unroll
            for (int i = 0; i < 4; ++i)
                myst[(quad * 4 + i) * 68 + nt * 16 + l16] = acc[nt][i];
#pragma unroll
        for (int rr = 0; rr < 4; ++rr) {
            const int row = rr * 4 + quad;
            float4 t4 = *(const float4*)&myst[row * 68 + l16 * 4];
            *(float4*)(f0 + (size_t)(m0 + row) * C_ + n0 + l16 * 4) = t4;
        }
    }
}

// ---------------- WKV combine: PARALLEL segmented scan over chunks ------------
__global__ __launch_bounds__(256) void wkv_combine_par(const float* __restrict__ decay,
                                                       float* __restrict__ sp,
                                                       float* __restrict__ sq,
                                                       float* __restrict__ so) {
    __shared__ float tp[16][17], tq[16][17], to[16][17];
    const int tid = threadIdx.x;
    const int cgi = tid >> 4;
    const int cl = tid & 15;
    const int b = blockIdx.x;
    const int c = blockIdx.y * 16 + cl;
    const float wL = decay[c] * (1.0f / T_) * (float)L_;
    const float wL16 = wL * 16.0f;
    const size_t base = ((size_t)b * NC_ + (size_t)cgi * 16) * C_ + c;

    float p = 0.f, q = 0.f, o = -1e38f;
#pragma unroll 4
    for (int j = 0; j < 16; ++j) {
        size_t idx = base + (size_t)j * C_;
        float lp = sp[idx], lq = sq[idx], lo = so[idx];
        float ow = o + wL;
        float no = fmaxf(ow, lo);
        float ea = __expf(ow - no), eb = __expf(lo - no);
        p = ea * p + eb * lp;
        q = ea * q + eb * lq;
        o = no;
    }
    tp[cgi][cl] = p; tq[cgi][cl] = q; to[cgi][cl] = o;

    float ip = p, iq = q, io = o;
#pragma unroll
    for (int off = 1; off < 16; off <<= 1) {
        __syncthreads();
        float ap = 0.f, aq = 0.f, ao = 0.f;
        const bool doit = (cgi >= off);
        if (doit) { ap = tp[cgi - off][cl]; aq = tq[cgi - off][cl]; ao = to[cgi - off][cl]; }
        __syncthreads();
        if (doit) {
            float ow = ao + (float)off * wL16;
            float no = fmaxf(ow, io);
            float ea = __expf(ow - no), eb = __expf(io - no);
            ip = ea * ap + eb * ip;
            iq = ea * aq + eb * iq;
            io = no;
            tp[cgi][cl] = ip; tq[cgi][cl] = iq; to[cgi][cl] = io;
        }
    }
    __syncthreads();

    float ep, eq, eo;
    if (cgi == 0) { ep = 0.f; eq = 0.f; eo = -1e38f; }
    else          { ep = tp[cgi - 1][cl]; eq = tq[cgi - 1][cl]; eo = to[cgi - 1][cl]; }

    for (int j = 0; j < 16; ++j) {
        size_t idx = base + (size_t)j * C_;
        float lp = sp[idx], lq = sq[idx], lo = so[idx];
        sp[idx] = ep; sq[idx] = eq; so[idx] = eo;
        float ow = eo + wL;
        float no = fmaxf(ow, lo);
        float ea = __expf(ow - no), eb = __expf(lo - no);
        ep = ea * ep + eb * lp;
        eq = ea * eq + eb * lq;
        eo = no;
    }
}

// ---------------- WKV pass 2 + LayerNorm + gate (known-good) -------------------
__global__ __launch_bounds__(256, 8) void wkv_pass2_ln(const float* __restrict__ k,
                                                       const float* __restrict__ v,
                                                       const unsigned short* __restrict__ sr,
                                                       const float* __restrict__ decay,
                                                       const float* __restrict__ first,
                                                       const float* __restrict__ lw,
                                                       const float* __restrict__ lb,
                                                       const float* __restrict__ sp,
                                                       const float* __restrict__ sq,
                                                       const float* __restrict__ so,
                                                       unsigned short* __restrict__ z) {
    __shared__ float tile[16][264];
    __shared__ float mu_s[16], rs_s[16];
    const int c = threadIdx.x, chunk = blockIdx.x, b = blockIdx.y;
    const int wave = c >> 6, lane = c & 63;
    const float w = decay[c] * (1.0f / T_);
    const float u = first[c] * (1.0f / T_);
    const float gw = lw[c], gb = lb[c];
    size_t sidx = ((size_t)b * NC_ + chunk) * C_ + c;
    float p = sp[sidx], q = sq[sidx], o = so[sidx];
    size_t base = ((size_t)b * T_ + (size_t)chunk * L_) * C_ + c;

    for (int t = 0; t < L_; t += 8) {
        float kk[8], vv[8];
#pragma unroll
        for (int j = 0; j < 8; ++j) {
            kk[j] = k[base + (size_t)(t + j) * C_];
            vv[j] = v[base + (size_t)(t + j) * C_];
        }
#pragma unroll
        for (int j = 0; j < 8; ++j) {
            float uk = u + kk[j];
            float no = fmaxf(o, uk);
            float a = __expf(o - no), bb = __expf(uk - no);
            tile[t + j][c] = (a * p + bb * vv[j]) / (a * q + bb);
            float wo = w + o;
            float no2 = fmaxf(wo, kk[j]);
            float a2 = __expf(wo - no2), b2 = __expf(kk[j] - no2);
            p = a2 * p + b2 * vv[j];
            q = a2 * q + b2;
            o = no2;
        }
    }
    __syncthreads();
#pragma unroll
    for (int r = 0; r < 4; ++r) {
        const int j = wave * 4 + r;
        float4 t4 = *(const float4*)&tile[j][lane * 4];
        float s = t4.x + t4.y + t4.z + t4.w;
        float ss = t4.x * t4.x + t4.y * t4.y + t4.z * t4.z + t4.w * t4.w;
#pragma unroll
        for (int m = 1; m < 64; m <<= 1) {
            s += __shfl_xor(s, m, 64);
            ss += __shfl_xor(ss, m, 64);
        }
        if (lane == 0) {
            float mu = s * (1.f / C_);
            mu_s[j] = mu;
            rs_s[j] = rsqrtf(ss * (1.f / C_) - mu * mu + 1e-5f);
        }
    }
    __syncthreads();
#pragma unroll
    for (int j = 0; j < L_; ++j) {
        float zz = (tile[j][c] - mu_s[j]) * rs_s[j] * gw + gb;
        zz *= b2f(sr[base + (size_t)j * C_]);
        z[base + (size_t)j * C_] = f2b(zz);
    }
}

extern "C" void kernel_launch(void* const* d_in, const int* in_sizes, int n_in,
                              void* d_out, int out_size, void* d_ws, size_t ws_size,
                              hipStream_t stream) {
    const float* x     = (const float*)d_in[0];
    const float* Wk    = (const float*)d_in[1];
    const float* Wv    = (const float*)d_in[2];
    const float* Wr    = (const float*)d_in[3];
    const float* Wo    = (const float*)d_in[4];
    const float* decay = (const float*)d_in[5];
    const float* first = (const float*)d_in[6];
    const float* lnw   = (const float*)d_in[7];
    const float* lnb   = (const float*)d_in[8];
    float* out = (float*)d_out;

    char* ws = (char*)d_ws;
    const size_t NE = (size_t)M_ * C_;              // 8388608
    unsigned short* wb  = (unsigned short*)ws; ws += 4 * 65536 * 2;  // wk|wv|wr|wo
    unsigned short* xb  = (unsigned short*)ws; ws += NE * 2;
    float* kbuf = (float*)ws; ws += NE * 4;
    float* vbuf = (float*)ws; ws += NE * 4;
    unsigned short* srb = (unsigned short*)ws; ws += NE * 2;
    unsigned short* zb  = (unsigned short*)ws; ws += NE * 2;
    const size_t SE = (size_t)B_ * NC_ * C_;        // 524288
    float* sp = (float*)ws; ws += SE * 4;
    float* sq = (float*)ws; ws += SE * 4;
    float* so = (float*)ws; ws += SE * 4;
    unsigned short* wkb = wb;
    unsigned short* wvb = wb + 65536;
    unsigned short* wrb = wb + 2 * 65536;
    unsigned short* wob = wb + 3 * 65536;

    cvt_all<<<4096 + 128, 256, 0, stream>>>(x, Wk, Wv, Wr, Wo, xb, wb);

    // QKV + fused pass1: 512 row-blocks x 4 col-strips = 2048 blocks
    gemm_qkv<<<dim3(M_ / 64, 4), 256, 0, stream>>>(xb, wkb, wvb, wrb, decay,
                                                   kbuf, vbuf, srb, sp, sq, so);

    wkv_combine_par<<<dim3(B_, C_ / 16), 256, 0, stream>>>(decay, sp, sq, so);
    wkv_pass2_ln<<<dim3(NC_, B_), 256, 0, stream>>>(kbuf, vbuf, srb, decay, first,
                                                    lnw, lnb, sp, sq, so, zb);

    // Output GEMM: 512 row-blocks, 4 n-strips looped inside
    gemm_out<<<dim3(M_ / 64), 256, 0, stream>>>(zb, wob, out);
}

// Round 13
// 159.606 us; speedup vs baseline: 1.2023x; 1.0449x over previous
//
#include <hip/hip_runtime.h>
#include <cstdint>
#include <cstddef>

#define B_ 8
#define T_ 4096
#define C_ 256
#define NC_ 256
#define L_ (T_ / NC_)   // 16 steps per chunk
#define M_ (B_ * T_)    // 32768 rows

typedef float f32x4 __attribute__((ext_vector_type(4)));
typedef short bf16x8 __attribute__((ext_vector_type(8)));

__device__ __forceinline__ unsigned short f2b(float f) {
    unsigned int u = __float_as_uint(f);
    u += 0x7fffu + ((u >> 16) & 1u);   // round-to-nearest-even
    return (unsigned short)(u >> 16);
}
__device__ __forceinline__ float b2f(unsigned short h) {
    return __uint_as_float(((unsigned int)h) << 16);
}

// ---------------- fused f32->bf16 convert: x (4096 blocks) + 4 weights --------
__global__ __launch_bounds__(256) void cvt_all(const float* __restrict__ x,
                                               const float* __restrict__ Wk,
                                               const float* __restrict__ Wv,
                                               const float* __restrict__ Wr,
                                               const float* __restrict__ Wo,
                                               unsigned short* __restrict__ xb,
                                               unsigned short* __restrict__ wb) {
    const int bid = blockIdx.x;
    const float* src;
    unsigned short* dst;
    size_t base;
    if (bid < 4096) {
        src = x; dst = xb;
        base = (size_t)bid * 2048;
    } else {
        const int r = bid - 4096;          // 0..127
        const int mat = r >> 5;            // 0..3
        src = (mat == 0) ? Wk : (mat == 1) ? Wv : (mat == 2) ? Wr : Wo;
        dst = wb + (size_t)mat * 65536;
        base = (size_t)(r & 31) * 2048;
    }
    const size_t i = base + (size_t)threadIdx.x * 8;
    float4 a = *(const float4*)(src + i);
    float4 b = *(const float4*)(src + i + 4);
    bf16x8 o;
    o[0] = (short)f2b(a.x); o[1] = (short)f2b(a.y);
    o[2] = (short)f2b(a.z); o[3] = (short)f2b(a.w);
    o[4] = (short)f2b(b.x); o[5] = (short)f2b(b.y);
    o[6] = (short)f2b(b.z); o[7] = (short)f2b(b.w);
    *(bf16x8*)(dst + i) = o;
}

// ---------------- QKV GEMM: fused pass1, bf16 k/v storage ----------------------
// O[m,n] = sum_k A[m,k]*W[n,k]. Grid (M/64, 4). 3 mats looped; W prefetched;
// fused pass1 scan. NEW (R13): k,v stored as bf16 (halves the k/v round-trip:
// 64->32 MB write here, 64->32 MB read in pass2). The fused scan snapshots the
// ROUNDED values so it is bit-consistent with what pass2 reads.
// R10/R11 lesson: separate stage buffer (no wlds aliasing). (256,3): no reg cap.
__global__ __launch_bounds__(256, 3) void gemm_qkv(const unsigned short* __restrict__ A,
                                                   const unsigned short* __restrict__ w0,
                                                   const unsigned short* __restrict__ w1,
                                                   const unsigned short* __restrict__ w2,
                                                   const float* __restrict__ decay,
                                                   unsigned short* __restrict__ kb,
                                                   unsigned short* __restrict__ vb,
                                                   unsigned short* __restrict__ b2,
                                                   float* __restrict__ sp,
                                                   float* __restrict__ sq,
                                                   float* __restrict__ so) {
    __shared__ unsigned short wlds[64 * 264];   // 33792 B
    __shared__ float stage[4][16 * 68];         // 17408 B (total 51200 -> 3 blk/CU)
    const int tid = threadIdx.x;
    const int wave = tid >> 6, lane = tid & 63;
    const int quad = lane >> 4, l16 = lane & 15;
    const int m0 = blockIdx.x * 64 + wave * 16;
    const int n0 = blockIdx.y * 64;
    float* myst = stage[wave];

    bf16x8 af[8];
    {
        const unsigned short* Ar = A + (size_t)(m0 + l16) * C_ + quad * 8;
#pragma unroll
        for (int kc = 0; kc < 8; ++kc) af[kc] = *(const bf16x8*)(Ar + kc * 32);
    }

    const int r = tid >> 5;              // 0..7
    const int cs = (tid & 31) * 8;       // short offset, 16 B per lane

    bf16x8 tmp[8];
#pragma unroll
    for (int it = 0; it < 8; ++it)
        tmp[it] = *(const bf16x8*)(w0 + (size_t)(n0 + it * 8 + r) * C_ + cs);

    float kreg[16], vreg[16];            // chunk-local k/v (bf16-rounded)

    for (int mat = 0; mat < 3; ++mat) {
        __syncthreads();                 // prev mat's wlds reads done
#pragma unroll
        for (int it = 0; it < 8; ++it)
            *(bf16x8*)(wlds + (it * 8 + r) * 264 + cs) = tmp[it];
        __syncthreads();                 // wlds visible to all waves

        if (mat < 2) {                   // prefetch next W; retires under MFMAs
            const unsigned short* Wn = (mat == 0) ? w1 : w2;
#pragma unroll
            for (int it = 0; it < 8; ++it)
                tmp[it] = *(const bf16x8*)(Wn + (size_t)(n0 + it * 8 + r) * C_ + cs);
        }

        f32x4 acc[4];
#pragma unroll
        for (int nt = 0; nt < 4; ++nt) acc[nt] = (f32x4){0.f, 0.f, 0.f, 0.f};
#pragma unroll
        for (int nt = 0; nt < 4; ++nt) {
            const unsigned short* wrow = wlds + (nt * 16 + l16) * 264 + quad * 8;
#pragma unroll
            for (int kc = 0; kc < 8; ++kc) {
                bf16x8 wf = *(const bf16x8*)(wrow + kc * 32);
                acc[nt] = __builtin_amdgcn_mfma_f32_16x16x32_bf16(af[kc], wf, acc[nt], 0, 0, 0);
            }
        }

#pragma unroll
        for (int nt = 0; nt < 4; ++nt)
#pragma unroll
            for (int i = 0; i < 4; ++i)
                myst[(quad * 4 + i) * 68 + nt * 16 + l16] = acc[nt][i];
#pragma unroll
        for (int rr = 0; rr < 4; ++rr) {
            const int row = rr * 4 + quad;
            float4 t4 = *(const float4*)&myst[row * 68 + l16 * 4];
            const size_t gidx = (size_t)(m0 + row) * C_ + n0 + l16 * 4;
            ushort4 s4;
            if (mat == 2) {
                s4.x = f2b(1.f / (1.f + __expf(-t4.x)));
                s4.y = f2b(1.f / (1.f + __expf(-t4.y)));
                s4.z = f2b(1.f / (1.f + __expf(-t4.z)));
                s4.w = f2b(1.f / (1.f + __expf(-t4.w)));
                *(ushort4*)(b2 + gidx) = s4;
            } else {
                s4.x = f2b(t4.x); s4.y = f2b(t4.y);
                s4.z = f2b(t4.z); s4.w = f2b(t4.w);
                unsigned short* Fb = (mat == 0) ? kb : vb;
                *(ushort4*)(Fb + gidx) = s4;
            }
        }

        // ---- fused pass1: snapshot ROUNDED chunk column, scan at mat==1 ----
        // myst is per-wave (wave-ordered LDS; separate buffer from wlds).
        if (mat == 0) {
#pragma unroll
            for (int j = 0; j < L_; ++j) kreg[j] = b2f(f2b(myst[j * 68 + lane]));
        } else if (mat == 1) {
#pragma unroll
            for (int j = 0; j < L_; ++j) vreg[j] = b2f(f2b(myst[j * 68 + lane]));
            const int ch = n0 + lane;
            const float w = decay[ch] * (1.0f / T_);
            float p = 0.f, q = 0.f, o = -1e38f;
#pragma unroll
            for (int j = 0; j < L_; ++j) {
                float wo = w + o;
                float no = fmaxf(wo, kreg[j]);
                float a2 = __expf(wo - no), b2s = __expf(kreg[j] - no);
                p = a2 * p + b2s * vreg[j];
                q = a2 * q + b2s;
                o = no;
            }
            const int bb = m0 / T_;
            const int chunk = (m0 % T_) / L_;
            const size_t idx = ((size_t)bb * NC_ + chunk) * C_ + ch;
            sp[idx] = p; sq[idx] = q; so[idx] = o;
        }
    }
}

// ---------------- output GEMM: 4 n-strips looped, A-frags loaded ONCE ---------
__global__ __launch_bounds__(256, 3) void gemm_out(const unsigned short* __restrict__ A,
                                                   const unsigned short* __restrict__ w0,
                                                   float* __restrict__ f0) {
    __shared__ unsigned short wlds[64 * 264];   // 33792 B
    __shared__ float stage[4][16 * 68];         // 17408 B
    const int tid = threadIdx.x;
    const int wave = tid >> 6, lane = tid & 63;
    const int quad = lane >> 4, l16 = lane & 15;
    const int m0 = blockIdx.x * 64 + wave * 16;
    float* myst = stage[wave];

    bf16x8 af[8];
    {
        const unsigned short* Ar = A + (size_t)(m0 + l16) * C_ + quad * 8;
#pragma unroll
        for (int kc = 0; kc < 8; ++kc) af[kc] = *(const bf16x8*)(Ar + kc * 32);
    }

    const int r = tid >> 5;              // 0..7
    const int cs = (tid & 31) * 8;       // short offset, 16 B per lane

    bf16x8 tmp[8];
#pragma unroll
    for (int it = 0; it < 8; ++it)
        tmp[it] = *(const bf16x8*)(w0 + (size_t)(it * 8 + r) * C_ + cs);

    for (int s = 0; s < 4; ++s) {
        const int n0 = s * 64;
        __syncthreads();                 // prev strip's wlds reads done
#pragma unroll
        for (int it = 0; it < 8; ++it)
            *(bf16x8*)(wlds + (it * 8 + r) * 264 + cs) = tmp[it];
        __syncthreads();                 // wlds visible to all waves

        if (s < 3) {                     // prefetch next strip's W rows
#pragma unroll
            for (int it = 0; it < 8; ++it)
                tmp[it] = *(const bf16x8*)(w0 + (size_t)(n0 + 64 + it * 8 + r) * C_ + cs);
        }

        f32x4 acc[4];
#pragma unroll
        for (int nt = 0; nt < 4; ++nt) acc[nt] = (f32x4){0.f, 0.f, 0.f, 0.f};
#pragma unroll
        for (int nt = 0; nt < 4; ++nt) {
            const unsigned short* wrow = wlds + (nt * 16 + l16) * 264 + quad * 8;
#pragma unroll
            for (int kc = 0; kc < 8; ++kc) {
                bf16x8 wf = *(const bf16x8*)(wrow + kc * 32);
                acc[nt] = __builtin_amdgcn_mfma_f32_16x16x32_bf16(af[kc], wf, acc[nt], 0, 0, 0);
            }
        }

#pragma unroll
        for (int nt = 0; nt < 4; ++nt)
#pragma unroll
            for (int i = 0; i < 4; ++i)
                myst[(quad * 4 + i) * 68 + nt * 16 + l16] = acc[nt][i];
#pragma unroll
        for (int rr = 0; rr < 4; ++rr) {
            const int row = rr * 4 + quad;
            float4 t4 = *(const float4*)&myst[row * 68 + l16 * 4];
            *(float4*)(f0 + (size_t)(m0 + row) * C_ + n0 + l16 * 4) = t4;
        }
    }
}

// ---------------- WKV combine: PARALLEL segmented scan over chunks ------------
__global__ __launch_bounds__(256) void wkv_combine_par(const float* __restrict__ decay,
                                                       float* __restrict__ sp,
                                                       float* __restrict__ sq,
                                                       float* __restrict__ so) {
    __shared__ float tp[16][17], tq[16][17], to[16][17];
    const int tid = threadIdx.x;
    const int cgi = tid >> 4;
    const int cl = tid & 15;
    const int b = blockIdx.x;
    const int c = blockIdx.y * 16 + cl;
    const float wL = decay[c] * (1.0f / T_) * (float)L_;
    const float wL16 = wL * 16.0f;
    const size_t base = ((size_t)b * NC_ + (size_t)cgi * 16) * C_ + c;

    float p = 0.f, q = 0.f, o = -1e38f;
#pragma unroll 4
    for (int j = 0; j < 16; ++j) {
        size_t idx = base + (size_t)j * C_;
        float lp = sp[idx], lq = sq[idx], lo = so[idx];
        float ow = o + wL;
        float no = fmaxf(ow, lo);
        float ea = __expf(ow - no), eb = __expf(lo - no);
        p = ea * p + eb * lp;
        q = ea * q + eb * lq;
        o = no;
    }
    tp[cgi][cl] = p; tq[cgi][cl] = q; to[cgi][cl] = o;

    float ip = p, iq = q, io = o;
#pragma unroll
    for (int off = 1; off < 16; off <<= 1) {
        __syncthreads();
        float ap = 0.f, aq = 0.f, ao = 0.f;
        const bool doit = (cgi >= off);
        if (doit) { ap = tp[cgi - off][cl]; aq = tq[cgi - off][cl]; ao = to[cgi - off][cl]; }
        __syncthreads();
        if (doit) {
            float ow = ao + (float)off * wL16;
            float no = fmaxf(ow, io);
            float ea = __expf(ow - no), eb = __expf(io - no);
            ip = ea * ap + eb * ip;
            iq = ea * aq + eb * iq;
            io = no;
            tp[cgi][cl] = ip; tq[cgi][cl] = iq; to[cgi][cl] = io;
        }
    }
    __syncthreads();

    float ep, eq, eo;
    if (cgi == 0) { ep = 0.f; eq = 0.f; eo = -1e38f; }
    else          { ep = tp[cgi - 1][cl]; eq = tq[cgi - 1][cl]; eo = to[cgi - 1][cl]; }

    for (int j = 0; j < 16; ++j) {
        size_t idx = base + (size_t)j * C_;
        float lp = sp[idx], lq = sq[idx], lo = so[idx];
        sp[idx] = ep; sq[idx] = eq; so[idx] = eo;
        float ow = eo + wL;
        float no = fmaxf(ow, lo);
        float ea = __expf(ow - no), eb = __expf(lo - no);
        ep = ea * ep + eb * lp;
        eq = ea * eq + eb * lq;
        eo = no;
    }
}

// ---------------- WKV pass 2 + LayerNorm + gate (bf16 k/v inputs) --------------
__global__ __launch_bounds__(256, 8) void wkv_pass2_ln(const unsigned short* __restrict__ k,
                                                       const unsigned short* __restrict__ v,
                                                       const unsigned short* __restrict__ sr,
                                                       const float* __restrict__ decay,
                                                       const float* __restrict__ first,
                                                       const float* __restrict__ lw,
                                                       const float* __restrict__ lb,
                                                       const float* __restrict__ sp,
                                                       const float* __restrict__ sq,
                                                       const float* __restrict__ so,
                                                       unsigned short* __restrict__ z) {
    __shared__ float tile[16][264];
    __shared__ float mu_s[16], rs_s[16];
    const int c = threadIdx.x, chunk = blockIdx.x, b = blockIdx.y;
    const int wave = c >> 6, lane = c & 63;
    const float w = decay[c] * (1.0f / T_);
    const float u = first[c] * (1.0f / T_);
    const float gw = lw[c], gb = lb[c];
    size_t sidx = ((size_t)b * NC_ + chunk) * C_ + c;
    float p = sp[sidx], q = sq[sidx], o = so[sidx];
    size_t base = ((size_t)b * T_ + (size_t)chunk * L_) * C_ + c;

    for (int t = 0; t < L_; t += 8) {
        float kk[8], vv[8];
#pragma unroll
        for (int j = 0; j < 8; ++j) {
            kk[j] = b2f(k[base + (size_t)(t + j) * C_]);
            vv[j] = b2f(v[base + (size_t)(t + j) * C_]);
        }
#pragma unroll
        for (int j = 0; j < 8; ++j) {
            float uk = u + kk[j];
            float no = fmaxf(o, uk);
            float a = __expf(o - no), bb = __expf(uk - no);
            tile[t + j][c] = (a * p + bb * vv[j]) / (a * q + bb);
            float wo = w + o;
            float no2 = fmaxf(wo, kk[j]);
            float a2 = __expf(wo - no2), b2 = __expf(kk[j] - no2);
            p = a2 * p + b2 * vv[j];
            q = a2 * q + b2;
            o = no2;
        }
    }
    __syncthreads();
#pragma unroll
    for (int r = 0; r < 4; ++r) {
        const int j = wave * 4 + r;
        float4 t4 = *(const float4*)&tile[j][lane * 4];
        float s = t4.x + t4.y + t4.z + t4.w;
        float ss = t4.x * t4.x + t4.y * t4.y + t4.z * t4.z + t4.w * t4.w;
#pragma unroll
        for (int m = 1; m < 64; m <<= 1) {
            s += __shfl_xor(s, m, 64);
            ss += __shfl_xor(ss, m, 64);
        }
        if (lane == 0) {
            float mu = s * (1.f / C_);
            mu_s[j] = mu;
            rs_s[j] = rsqrtf(ss * (1.f / C_) - mu * mu + 1e-5f);
        }
    }
    __syncthreads();
#pragma unroll
    for (int j = 0; j < L_; ++j) {
        float zz = (tile[j][c] - mu_s[j]) * rs_s[j] * gw + gb;
        zz *= b2f(sr[base + (size_t)j * C_]);
        z[base + (size_t)j * C_] = f2b(zz);
    }
}

extern "C" void kernel_launch(void* const* d_in, const int* in_sizes, int n_in,
                              void* d_out, int out_size, void* d_ws, size_t ws_size,
                              hipStream_t stream) {
    const float* x     = (const float*)d_in[0];
    const float* Wk    = (const float*)d_in[1];
    const float* Wv    = (const float*)d_in[2];
    const float* Wr    = (const float*)d_in[3];
    const float* Wo    = (const float*)d_in[4];
    const float* decay = (const float*)d_in[5];
    const float* first = (const float*)d_in[6];
    const float* lnw   = (const float*)d_in[7];
    const float* lnb   = (const float*)d_in[8];
    float* out = (float*)d_out;

    char* ws = (char*)d_ws;
    const size_t NE = (size_t)M_ * C_;              // 8388608
    unsigned short* wb  = (unsigned short*)ws; ws += 4 * 65536 * 2;  // wk|wv|wr|wo
    unsigned short* xb  = (unsigned short*)ws; ws += NE * 2;
    unsigned short* kbuf = (unsigned short*)ws; ws += NE * 2;        // bf16 k
    unsigned short* vbuf = (unsigned short*)ws; ws += NE * 2;        // bf16 v
    unsigned short* srb = (unsigned short*)ws; ws += NE * 2;
    unsigned short* zb  = (unsigned short*)ws; ws += NE * 2;
    const size_t SE = (size_t)B_ * NC_ * C_;        // 524288
    float* sp = (float*)ws; ws += SE * 4;
    float* sq = (float*)ws; ws += SE * 4;
    float* so = (float*)ws; ws += SE * 4;
    unsigned short* wkb = wb;
    unsigned short* wvb = wb + 65536;
    unsigned short* wrb = wb + 2 * 65536;
    unsigned short* wob = wb + 3 * 65536;

    cvt_all<<<4096 + 128, 256, 0, stream>>>(x, Wk, Wv, Wr, Wo, xb, wb);

    // QKV + fused pass1: 512 row-blocks x 4 col-strips = 2048 blocks
    gemm_qkv<<<dim3(M_ / 64, 4), 256, 0, stream>>>(xb, wkb, wvb, wrb, decay,
                                                   kbuf, vbuf, srb, sp, sq, so);

    wkv_combine_par<<<dim3(B_, C_ / 16), 256, 0, stream>>>(decay, sp, sq, so);
    wkv_pass2_ln<<<dim3(NC_, B_), 256, 0, stream>>>(kbuf, vbuf, srb, decay, first,
                                                    lnw, lnb, sp, sq, so, zb);

    // Output GEMM: 512 row-blocks, 4 n-strips looped inside
    gemm_out<<<dim3(M_ / 64), 256, 0, stream>>>(zb, wob, out);
}

// Round 14
// 156.957 us; speedup vs baseline: 1.2225x; 1.0169x over previous
//
#include <hip/hip_runtime.h>
#include <cstdint>
#include <cstddef>

#define B_ 8
#define T_ 4096
#define C_ 256
#define NC_ 256
#define L_ (T_ / NC_)   // 16 steps per chunk
#define M_ (B_ * T_)    // 32768 rows

typedef float f32x4 __attribute__((ext_vector_type(4)));
typedef short bf16x8 __attribute__((ext_vector_type(8)));

__device__ __forceinline__ unsigned short f2b(float f) {
    unsigned int u = __float_as_uint(f);
    u += 0x7fffu + ((u >> 16) & 1u);   // round-to-nearest-even
    return (unsigned short)(u >> 16);
}
__device__ __forceinline__ float b2f(unsigned short h) {
    return __uint_as_float(((unsigned int)h) << 16);
}

// ---------------- f32->bf16 convert: WEIGHTS ONLY (x fused into gemm_qkv) -----
__global__ __launch_bounds__(256) void cvt_w(const float* __restrict__ Wk,
                                             const float* __restrict__ Wv,
                                             const float* __restrict__ Wr,
                                             const float* __restrict__ Wo,
                                             unsigned short* __restrict__ wb) {
    const int r = blockIdx.x;              // 0..127
    const int mat = r >> 5;                // 0..3
    const float* src = (mat == 0) ? Wk : (mat == 1) ? Wv : (mat == 2) ? Wr : Wo;
    unsigned short* dst = wb + (size_t)mat * 65536;
    const size_t i = (size_t)(r & 31) * 2048 + (size_t)threadIdx.x * 8;
    float4 a = *(const float4*)(src + i);
    float4 b = *(const float4*)(src + i + 4);
    bf16x8 o;
    o[0] = (short)f2b(a.x); o[1] = (short)f2b(a.y);
    o[2] = (short)f2b(a.z); o[3] = (short)f2b(a.w);
    o[4] = (short)f2b(b.x); o[5] = (short)f2b(b.y);
    o[6] = (short)f2b(b.z); o[7] = (short)f2b(b.w);
    *(bf16x8*)(dst + i) = o;
}

// ---------------- QKV GEMM v10: strip-looped, direct f32 x, fused pass1 -------
// O[m,n] = sum_k A[m,k]*W[n,k], A = bf16(x) converted in-register (bit-identical
// to the old cvt_all path). Grid (M/64) = 512 blocks, ALL co-resident (3/CU
// cap). The 4 n-strips AND 3 mats loop in-block (12 phases), so each x row is
// read exactly ONCE device-wide -- this is what makes direct-f32-x safe (R5's
// failure was the 4-strip grid re-reading x 4x). W is L2-resident (512 KB).
// k/v stored bf16 (R13); fused pass1 scan per (strip, mat==1). Separate stage
// buffer (R11 lesson); no reg cap beyond (256,3) (R10 lesson).
__global__ __launch_bounds__(256, 3) void gemm_qkv(const float* __restrict__ x,
                                                   const unsigned short* __restrict__ w0,
                                                   const unsigned short* __restrict__ w1,
                                                   const unsigned short* __restrict__ w2,
                                                   const float* __restrict__ decay,
                                                   unsigned short* __restrict__ kb,
                                                   unsigned short* __restrict__ vb,
                                                   unsigned short* __restrict__ b2,
                                                   float* __restrict__ sp,
                                                   float* __restrict__ sq,
                                                   float* __restrict__ so) {
    __shared__ unsigned short wlds[64 * 264];   // 33792 B
    __shared__ float stage[4][16 * 68];         // 17408 B (total 51200 -> 3 blk/CU)
    const int tid = threadIdx.x;
    const int wave = tid >> 6, lane = tid & 63;
    const int quad = lane >> 4, l16 = lane & 15;
    const int m0 = blockIdx.x * 64 + wave * 16;
    float* myst = stage[wave];

    // A fragments from f32 x, converted in-register (bit-identical to cvt path)
    bf16x8 af[8];
    {
        const float* Ar = x + (size_t)(m0 + l16) * C_ + quad * 8;
#pragma unroll
        for (int kc = 0; kc < 8; ++kc) {
            float4 a = *(const float4*)(Ar + kc * 32);
            float4 b = *(const float4*)(Ar + kc * 32 + 4);
            bf16x8 o;
            o[0] = (short)f2b(a.x); o[1] = (short)f2b(a.y);
            o[2] = (short)f2b(a.z); o[3] = (short)f2b(a.w);
            o[4] = (short)f2b(b.x); o[5] = (short)f2b(b.y);
            o[6] = (short)f2b(b.z); o[7] = (short)f2b(b.w);
            af[kc] = o;
        }
    }

    const int r = tid >> 5;              // 0..7
    const int cs = (tid & 31) * 8;       // short offset, 16 B per lane

    bf16x8 tmp[8];
#pragma unroll
    for (int it = 0; it < 8; ++it)
        tmp[it] = *(const bf16x8*)(w0 + (size_t)(it * 8 + r) * C_ + cs);

    float kreg[16], vreg[16];            // chunk-local k/v (bf16-rounded)

    for (int s = 0; s < 4; ++s) {
        const int n0 = s * 64;
        for (int mat = 0; mat < 3; ++mat) {
            __syncthreads();             // prev phase's wlds reads done
#pragma unroll
            for (int it = 0; it < 8; ++it)
                *(bf16x8*)(wlds + (it * 8 + r) * 264 + cs) = tmp[it];
            __syncthreads();             // wlds visible to all waves

            if (!(s == 3 && mat == 2)) { // prefetch next phase's W tile
                const unsigned short* Wn = (mat == 0) ? w1 : (mat == 1) ? w2 : w0;
                const int nn = (mat == 2) ? n0 + 64 : n0;
#pragma unroll
                for (int it = 0; it < 8; ++it)
                    tmp[it] = *(const bf16x8*)(Wn + (size_t)(nn + it * 8 + r) * C_ + cs);
            }

            f32x4 acc[4];
#pragma unroll
            for (int nt = 0; nt < 4; ++nt) acc[nt] = (f32x4){0.f, 0.f, 0.f, 0.f};
#pragma unroll
            for (int nt = 0; nt < 4; ++nt) {
                const unsigned short* wrow = wlds + (nt * 16 + l16) * 264 + quad * 8;
#pragma unroll
                for (int kc = 0; kc < 8; ++kc) {
                    bf16x8 wf = *(const bf16x8*)(wrow + kc * 32);
                    acc[nt] = __builtin_amdgcn_mfma_f32_16x16x32_bf16(af[kc], wf, acc[nt], 0, 0, 0);
                }
            }

#pragma unroll
            for (int nt = 0; nt < 4; ++nt)
#pragma unroll
                for (int i = 0; i < 4; ++i)
                    myst[(quad * 4 + i) * 68 + nt * 16 + l16] = acc[nt][i];
#pragma unroll
            for (int rr = 0; rr < 4; ++rr) {
                const int row = rr * 4 + quad;
                float4 t4 = *(const float4*)&myst[row * 68 + l16 * 4];
                const size_t gidx = (size_t)(m0 + row) * C_ + n0 + l16 * 4;
                ushort4 s4;
                if (mat == 2) {
                    s4.x = f2b(1.f / (1.f + __expf(-t4.x)));
                    s4.y = f2b(1.f / (1.f + __expf(-t4.y)));
                    s4.z = f2b(1.f / (1.f + __expf(-t4.z)));
                    s4.w = f2b(1.f / (1.f + __expf(-t4.w)));
                    *(ushort4*)(b2 + gidx) = s4;
                } else {
                    s4.x = f2b(t4.x); s4.y = f2b(t4.y);
                    s4.z = f2b(t4.z); s4.w = f2b(t4.w);
                    unsigned short* Fb = (mat == 0) ? kb : vb;
                    *(ushort4*)(Fb + gidx) = s4;
                }
            }

            // ---- fused pass1 for this strip's 64 channels --------------------
            // myst is per-wave (wave-ordered LDS; separate buffer from wlds).
            if (mat == 0) {
#pragma unroll
                for (int j = 0; j < L_; ++j) kreg[j] = b2f(f2b(myst[j * 68 + lane]));
            } else if (mat == 1) {
#pragma unroll
                for (int j = 0; j < L_; ++j) vreg[j] = b2f(f2b(myst[j * 68 + lane]));
                const int ch = n0 + lane;
                const float w = decay[ch] * (1.0f / T_);
                float p = 0.f, q = 0.f, o = -1e38f;
#pragma unroll
                for (int j = 0; j < L_; ++j) {
                    float wo = w + o;
                    float no = fmaxf(wo, kreg[j]);
                    float a2 = __expf(wo - no), b2s = __expf(kreg[j] - no);
                    p = a2 * p + b2s * vreg[j];
                    q = a2 * q + b2s;
                    o = no;
                }
                const int bb = m0 / T_;
                const int chunk = (m0 % T_) / L_;
                const size_t idx = ((size_t)bb * NC_ + chunk) * C_ + ch;
                sp[idx] = p; sq[idx] = q; so[idx] = o;
            }
        }
    }
}

// ---------------- output GEMM: 4 n-strips looped, A-frags loaded ONCE ---------
__global__ __launch_bounds__(256, 3) void gemm_out(const unsigned short* __restrict__ A,
                                                   const unsigned short* __restrict__ w0,
                                                   float* __restrict__ f0) {
    __shared__ unsigned short wlds[64 * 264];   // 33792 B
    __shared__ float stage[4][16 * 68];         // 17408 B
    const int tid = threadIdx.x;
    const int wave = tid >> 6, lane = tid & 63;
    const int quad = lane >> 4, l16 = lane & 15;
    const int m0 = blockIdx.x * 64 + wave * 16;
    float* myst = stage[wave];

    bf16x8 af[8];
    {
        const unsigned short* Ar = A + (size_t)(m0 + l16) * C_ + quad * 8;
#pragma unroll
        for (int kc = 0; kc < 8; ++kc) af[kc] = *(const bf16x8*)(Ar + kc * 32);
    }

    const int r = tid >> 5;              // 0..7
    const int cs = (tid & 31) * 8;       // short offset, 16 B per lane

    bf16x8 tmp[8];
#pragma unroll
    for (int it = 0; it < 8; ++it)
        tmp[it] = *(const bf16x8*)(w0 + (size_t)(it * 8 + r) * C_ + cs);

    for (int s = 0; s < 4; ++s) {
        const int n0 = s * 64;
        __syncthreads();                 // prev strip's wlds reads done
#pragma unroll
        for (int it = 0; it < 8; ++it)
            *(bf16x8*)(wlds + (it * 8 + r) * 264 + cs) = tmp[it];
        __syncthreads();                 // wlds visible to all waves

        if (s < 3) {                     // prefetch next strip's W rows
#pragma unroll
            for (int it = 0; it < 8; ++it)
                tmp[it] = *(const bf16x8*)(w0 + (size_t)(n0 + 64 + it * 8 + r) * C_ + cs);
        }

        f32x4 acc[4];
#pragma unroll
        for (int nt = 0; nt < 4; ++nt) acc[nt] = (f32x4){0.f, 0.f, 0.f, 0.f};
#pragma unroll
        for (int nt = 0; nt < 4; ++nt) {
            const unsigned short* wrow = wlds + (nt * 16 + l16) * 264 + quad * 8;
#pragma unroll
            for (int kc = 0; kc < 8; ++kc) {
                bf16x8 wf = *(const bf16x8*)(wrow + kc * 32);
                acc[nt] = __builtin_amdgcn_mfma_f32_16x16x32_bf16(af[kc], wf, acc[nt], 0, 0, 0);
            }
        }

#pragma unroll
        for (int nt = 0; nt < 4; ++nt)
#pragma unroll
            for (int i = 0; i < 4; ++i)
                myst[(quad * 4 + i) * 68 + nt * 16 + l16] = acc[nt][i];
#pragma unroll
        for (int rr = 0; rr < 4; ++rr) {
            const int row = rr * 4 + quad;
            float4 t4 = *(const float4*)&myst[row * 68 + l16 * 4];
            *(float4*)(f0 + (size_t)(m0 + row) * C_ + n0 + l16 * 4) = t4;
        }
    }
}

// ---------------- WKV combine: PARALLEL segmented scan over chunks ------------
__global__ __launch_bounds__(256) void wkv_combine_par(const float* __restrict__ decay,
                                                       float* __restrict__ sp,
                                                       float* __restrict__ sq,
                                                       float* __restrict__ so) {
    __shared__ float tp[16][17], tq[16][17], to[16][17];
    const int tid = threadIdx.x;
    const int cgi = tid >> 4;
    const int cl = tid & 15;
    const int b = blockIdx.x;
    const int c = blockIdx.y * 16 + cl;
    const float wL = decay[c] * (1.0f / T_) * (float)L_;
    const float wL16 = wL * 16.0f;
    const size_t base = ((size_t)b * NC_ + (size_t)cgi * 16) * C_ + c;

    float p = 0.f, q = 0.f, o = -1e38f;
#pragma unroll 4
    for (int j = 0; j < 16; ++j) {
        size_t idx = base + (size_t)j * C_;
        float lp = sp[idx], lq = sq[idx], lo = so[idx];
        float ow = o + wL;
        float no = fmaxf(ow, lo);
        float ea = __expf(ow - no), eb = __expf(lo - no);
        p = ea * p + eb * lp;
        q = ea * q + eb * lq;
        o = no;
    }
    tp[cgi][cl] = p; tq[cgi][cl] = q; to[cgi][cl] = o;

    float ip = p, iq = q, io = o;
#pragma unroll
    for (int off = 1; off < 16; off <<= 1) {
        __syncthreads();
        float ap = 0.f, aq = 0.f, ao = 0.f;
        const bool doit = (cgi >= off);
        if (doit) { ap = tp[cgi - off][cl]; aq = tq[cgi - off][cl]; ao = to[cgi - off][cl]; }
        __syncthreads();
        if (doit) {
            float ow = ao + (float)off * wL16;
            float no = fmaxf(ow, io);
            float ea = __expf(ow - no), eb = __expf(io - no);
            ip = ea * ap + eb * ip;
            iq = ea * aq + eb * iq;
            io = no;
            tp[cgi][cl] = ip; tq[cgi][cl] = iq; to[cgi][cl] = io;
        }
    }
    __syncthreads();

    float ep, eq, eo;
    if (cgi == 0) { ep = 0.f; eq = 0.f; eo = -1e38f; }
    else          { ep = tp[cgi - 1][cl]; eq = tq[cgi - 1][cl]; eo = to[cgi - 1][cl]; }

    for (int j = 0; j < 16; ++j) {
        size_t idx = base + (size_t)j * C_;
        float lp = sp[idx], lq = sq[idx], lo = so[idx];
        sp[idx] = ep; sq[idx] = eq; so[idx] = eo;
        float ow = eo + wL;
        float no = fmaxf(ow, lo);
        float ea = __expf(ow - no), eb = __expf(lo - no);
        ep = ea * ep + eb * lp;
        eq = ea * eq + eb * lq;
        eo = no;
    }
}

// ---------------- WKV pass 2 + LayerNorm + gate (bf16 k/v inputs) --------------
__global__ __launch_bounds__(256, 8) void wkv_pass2_ln(const unsigned short* __restrict__ k,
                                                       const unsigned short* __restrict__ v,
                                                       const unsigned short* __restrict__ sr,
                                                       const float* __restrict__ decay,
                                                       const float* __restrict__ first,
                                                       const float* __restrict__ lw,
                                                       const float* __restrict__ lb,
                                                       const float* __restrict__ sp,
                                                       const float* __restrict__ sq,
                                                       const float* __restrict__ so,
                                                       unsigned short* __restrict__ z) {
    __shared__ float tile[16][264];
    __shared__ float mu_s[16], rs_s[16];
    const int c = threadIdx.x, chunk = blockIdx.x, b = blockIdx.y;
    const int wave = c >> 6, lane = c & 63;
    const float w = decay[c] * (1.0f / T_);
    const float u = first[c] * (1.0f / T_);
    const float gw = lw[c], gb = lb[c];
    size_t sidx = ((size_t)b * NC_ + chunk) * C_ + c;
    float p = sp[sidx], q = sq[sidx], o = so[sidx];
    size_t base = ((size_t)b * T_ + (size_t)chunk * L_) * C_ + c;

    for (int t = 0; t < L_; t += 8) {
        float kk[8], vv[8];
#pragma unroll
        for (int j = 0; j < 8; ++j) {
            kk[j] = b2f(k[base + (size_t)(t + j) * C_]);
            vv[j] = b2f(v[base + (size_t)(t + j) * C_]);
        }
#pragma unroll
        for (int j = 0; j < 8; ++j) {
            float uk = u + kk[j];
            float no = fmaxf(o, uk);
            float a = __expf(o - no), bb = __expf(uk - no);
            tile[t + j][c] = (a * p + bb * vv[j]) / (a * q + bb);
            float wo = w + o;
            float no2 = fmaxf(wo, kk[j]);
            float a2 = __expf(wo - no2), b2 = __expf(kk[j] - no2);
            p = a2 * p + b2 * vv[j];
            q = a2 * q + b2;
            o = no2;
        }
    }
    __syncthreads();
#pragma unroll
    for (int r = 0; r < 4; ++r) {
        const int j = wave * 4 + r;
        float4 t4 = *(const float4*)&tile[j][lane * 4];
        float s = t4.x + t4.y + t4.z + t4.w;
        float ss = t4.x * t4.x + t4.y * t4.y + t4.z * t4.z + t4.w * t4.w;
#pragma unroll
        for (int m = 1; m < 64; m <<= 1) {
            s += __shfl_xor(s, m, 64);
            ss += __shfl_xor(ss, m, 64);
        }
        if (lane == 0) {
            float mu = s * (1.f / C_);
            mu_s[j] = mu;
            rs_s[j] = rsqrtf(ss * (1.f / C_) - mu * mu + 1e-5f);
        }
    }
    __syncthreads();
#pragma unroll
    for (int j = 0; j < L_; ++j) {
        float zz = (tile[j][c] - mu_s[j]) * rs_s[j] * gw + gb;
        zz *= b2f(sr[base + (size_t)j * C_]);
        z[base + (size_t)j * C_] = f2b(zz);
    }
}

extern "C" void kernel_launch(void* const* d_in, const int* in_sizes, int n_in,
                              void* d_out, int out_size, void* d_ws, size_t ws_size,
                              hipStream_t stream) {
    const float* x     = (const float*)d_in[0];
    const float* Wk    = (const float*)d_in[1];
    const float* Wv    = (const float*)d_in[2];
    const float* Wr    = (const float*)d_in[3];
    const float* Wo    = (const float*)d_in[4];
    const float* decay = (const float*)d_in[5];
    const float* first = (const float*)d_in[6];
    const float* lnw   = (const float*)d_in[7];
    const float* lnb   = (const float*)d_in[8];
    float* out = (float*)d_out;

    char* ws = (char*)d_ws;
    const size_t NE = (size_t)M_ * C_;              // 8388608
    unsigned short* wb  = (unsigned short*)ws; ws += 4 * 65536 * 2;  // wk|wv|wr|wo
    unsigned short* kbuf = (unsigned short*)ws; ws += NE * 2;        // bf16 k
    unsigned short* vbuf = (unsigned short*)ws; ws += NE * 2;        // bf16 v
    unsigned short* srb = (unsigned short*)ws; ws += NE * 2;
    unsigned short* zb  = (unsigned short*)ws; ws += NE * 2;
    const size_t SE = (size_t)B_ * NC_ * C_;        // 524288
    float* sp = (float*)ws; ws += SE * 4;
    float* sq = (float*)ws; ws += SE * 4;
    float* so = (float*)ws; ws += SE * 4;
    unsigned short* wkb = wb;
    unsigned short* wvb = wb + 65536;
    unsigned short* wrb = wb + 2 * 65536;
    unsigned short* wob = wb + 3 * 65536;

    cvt_w<<<128, 256, 0, stream>>>(Wk, Wv, Wr, Wo, wb);

    // QKV + fused pass1: 512 row-blocks; 4 n-strips x 3 mats looped inside.
    // x read directly as f32 (exactly once device-wide), converted in-register.
    gemm_qkv<<<dim3(M_ / 64), 256, 0, stream>>>(x, wkb, wvb, wrb, decay,
                                                kbuf, vbuf, srb, sp, sq, so);

    wkv_combine_par<<<dim3(B_, C_ / 16), 256, 0, stream>>>(decay, sp, sq, so);
    wkv_pass2_ln<<<dim3(NC_, B_), 256, 0, stream>>>(kbuf, vbuf, srb, decay, first,
                                                    lnw, lnb, sp, sq, so, zb);

    // Output GEMM: 512 row-blocks, 4 n-strips looped inside
    gemm_out<<<dim3(M_ / 64), 256, 0, stream>>>(zb, wob, out);
}